// Round 1
// baseline (597.838 us; speedup 1.0000x reference)
//
#include <hip/hip_runtime.h>
#include <stdint.h>

// LocalGConv: out[b,u,o] = relu( sum_s sum_v adj[s,u,v] * (sum_i x[b,v,i]*W[s,i,o]) + bias[o] )
// B=32768, V=43, DIN=DOUT=64, S=2. fp32 in/out; bf16 MFMA internally (threshold 0.67 allows it).

#define BATCH 32768
#define NV 43
#define DIN 64
#define DOUT 64
#define NS 2

#define PSTRIDE 72   // pre_T row stride (bf16 elems): 144B = 16B-aligned, 2-way-bank only
#define ASTRIDE 72   // adj row stride
#define NWAVES 4

typedef __attribute__((ext_vector_type(8))) short short8;    // 8 bf16 (4 VGPRs) MFMA A/B frag
typedef __attribute__((ext_vector_type(4))) float f32x4;     // MFMA C/D frag
typedef __attribute__((ext_vector_type(4))) unsigned short ushort4_t;

__device__ __forceinline__ unsigned short f2bf(float f) {
    union { float f; unsigned int u; } x;
    x.f = f;
    unsigned int r = x.u + 0x7FFFu + ((x.u >> 16) & 1u);  // RNE
    return (unsigned short)(r >> 16);
}

__global__ void __launch_bounds__(256, 2) lgconv_kernel(
    const float* __restrict__ xg,
    const float* __restrict__ adjg,
    const float* __restrict__ wg,
    const float* __restrict__ bg,
    float* __restrict__ outg)
{
    // adj: [s][u(48 pad)][v(72 pad)] bf16, zero-padded. 13824 B
    __shared__ __align__(16) unsigned short s_adj[NS * 48 * ASTRIDE];
    // pre_T per wave: [o(64)][v(72 pad)] bf16; v in [48,64) stays zero. 36864 B
    __shared__ __align__(16) unsigned short s_pre[NWAVES * 64 * PSTRIDE];

    const int tid  = threadIdx.x;
    const int wave = tid >> 6;
    const int lane = tid & 63;
    const int quad = lane >> 4;
    const int l16  = lane & 15;

    // ---- setup A: stage W (bf16) into s_pre scratch, coalesced ----
    for (int t = tid; t < NS * DIN * DOUT; t += 256)
        s_pre[t] = f2bf(wg[t]);
    __syncthreads();

    // ---- setup B: each wave reads its W B-operand fragments into registers ----
    // B-frag layout (16x16x32): lane holds B[k = quad*8+j][n = l16]
    short8 wfrag[NS][2][4];   // [s][kchunk][ntile]
    for (int s = 0; s < NS; ++s)
      for (int kc = 0; kc < 2; ++kc)
        for (int nt = 0; nt < 4; ++nt) {
          short8 f;
          #pragma unroll
          for (int j = 0; j < 8; ++j) {
            int i = kc * 32 + quad * 8 + j;
            f[j] = (short)s_pre[(s * DIN + i) * DOUT + nt * 16 + l16];
          }
          wfrag[s][kc][nt] = f;
        }
    float biasv[4];
    #pragma unroll
    for (int nt = 0; nt < 4; ++nt) biasv[nt] = bg[nt * 16 + l16];
    __syncthreads();

    // ---- setup C: zero pre (pad must be 0) and adj; then fill adj (bf16) ----
    for (int t = tid; t < NWAVES * 64 * PSTRIDE; t += 256) s_pre[t] = 0;
    for (int t = tid; t < NS * 48 * ASTRIDE; t += 256) s_adj[t] = 0;
    __syncthreads();
    for (int t = tid; t < NS * NV * NV; t += 256) {
        int s  = t / (NV * NV);
        int rc = t - s * NV * NV;
        int r  = rc / NV;
        int c  = rc - r * NV;
        s_adj[(s * 48 + r) * ASTRIDE + c] = f2bf(adjg[t]);
    }
    __syncthreads();

    unsigned short* mypre = &s_pre[wave * 64 * PSTRIDE];
    const int gwave = blockIdx.x * NWAVES + wave;
    const int nwv   = gridDim.x * NWAVES;

    for (int b = gwave; b < BATCH; b += nwv) {
        // ---- load x[b] as MFMA A-frags: A[m = l16][k = quad*8+j], rows>=43 -> 0 ----
        short8 afrag[3][2];   // [mtile][kchunk]
        #pragma unroll
        for (int mt = 0; mt < 3; ++mt) {
            int m = mt * 16 + l16;
            bool valid = (m < NV);
            const float* p = xg + ((size_t)b * NV + m) * DIN + quad * 8;
            #pragma unroll
            for (int kc = 0; kc < 2; ++kc) {
                f32x4 u0 = {0.f, 0.f, 0.f, 0.f};
                f32x4 u1 = {0.f, 0.f, 0.f, 0.f};
                if (valid) {
                    u0 = *(const f32x4*)(p + kc * 32);
                    u1 = *(const f32x4*)(p + kc * 32 + 4);
                }
                short8 f;
                f[0] = (short)f2bf(u0[0]); f[1] = (short)f2bf(u0[1]);
                f[2] = (short)f2bf(u0[2]); f[3] = (short)f2bf(u0[3]);
                f[4] = (short)f2bf(u1[0]); f[5] = (short)f2bf(u1[1]);
                f[6] = (short)f2bf(u1[2]); f[7] = (short)f2bf(u1[3]);
                afrag[mt][kc] = f;
            }
        }

        f32x4 oacc[3][4];
        #pragma unroll
        for (int mt = 0; mt < 3; ++mt)
            #pragma unroll
            for (int nt = 0; nt < 4; ++nt)
                oacc[mt][nt] = (f32x4){0.f, 0.f, 0.f, 0.f};

        #pragma unroll
        for (int s = 0; s < NS; ++s) {
            // ---- stage1: pre = x[b] @ W[s]; write transposed bf16 to mypre ----
            #pragma unroll
            for (int mt = 0; mt < 3; ++mt) {
                #pragma unroll
                for (int nt = 0; nt < 4; ++nt) {
                    f32x4 c = (f32x4){0.f, 0.f, 0.f, 0.f};
                    c = __builtin_amdgcn_mfma_f32_16x16x32_bf16(afrag[mt][0], wfrag[s][0][nt], c, 0, 0, 0);
                    c = __builtin_amdgcn_mfma_f32_16x16x32_bf16(afrag[mt][1], wfrag[s][1][nt], c, 0, 0, 0);
                    // lane holds pre[v = mt*16+quad*4+r][o = nt*16+l16]; store pre_T[o][v..v+3]
                    ushort4_t pk;
                    pk[0] = f2bf(c[0]); pk[1] = f2bf(c[1]);
                    pk[2] = f2bf(c[2]); pk[3] = f2bf(c[3]);
                    int o  = nt * 16 + l16;
                    int v0 = mt * 16 + quad * 4;
                    *(ushort4_t*)(mypre + o * PSTRIDE + v0) = pk;
                }
            }
            __builtin_amdgcn_s_waitcnt(0xc07f);  // lgkmcnt(0): pre_T visible (wave-private; DS in-order)

            // ---- stage2: oacc += adj[s] @ pre  (K = 64, padded; pad region is 0) ----
            #pragma unroll
            for (int kc = 0; kc < 2; ++kc) {
                short8 bfr[4];
                #pragma unroll
                for (int nt = 0; nt < 4; ++nt)
                    bfr[nt] = *(const short8*)(mypre + (nt * 16 + l16) * PSTRIDE + kc * 32 + quad * 8);
                #pragma unroll
                for (int mt = 0; mt < 3; ++mt) {
                    short8 afr = *(const short8*)(&s_adj[(s * 48 + mt * 16 + l16) * ASTRIDE + kc * 32 + quad * 8]);
                    #pragma unroll
                    for (int nt = 0; nt < 4; ++nt)
                        oacc[mt][nt] = __builtin_amdgcn_mfma_f32_16x16x32_bf16(afr, bfr[nt], oacc[mt][nt], 0, 0, 0);
                }
            }
        }

        // ---- epilogue: bias + relu + store (rows u < 43) ----
        size_t obase = (size_t)b * (NV * DOUT);
        #pragma unroll
        for (int mt = 0; mt < 3; ++mt) {
            #pragma unroll
            for (int r = 0; r < 4; ++r) {
                int u = mt * 16 + quad * 4 + r;
                if (u < NV) {
                    #pragma unroll
                    for (int nt = 0; nt < 4; ++nt) {
                        float vv = oacc[mt][nt][r] + biasv[nt];
                        vv = fmaxf(vv, 0.0f);
                        outg[obase + (size_t)u * DOUT + nt * 16 + l16] = vv;
                    }
                }
            }
        }
    }
}

extern "C" void kernel_launch(void* const* d_in, const int* in_sizes, int n_in,
                              void* d_out, int out_size, void* d_ws, size_t ws_size,
                              hipStream_t stream) {
    (void)in_sizes; (void)n_in; (void)d_ws; (void)ws_size; (void)out_size;
    const float* xg   = (const float*)d_in[0];
    const float* adjg = (const float*)d_in[1];
    const float* wg   = (const float*)d_in[2];
    const float* bg   = (const float*)d_in[3];
    float* outg = (float*)d_out;

    dim3 grid(1024), block(256);
    hipLaunchKernelGGL(lgconv_kernel, grid, block, 0, stream, xg, adjg, wg, bg, outg);
}